// Round 2
// baseline (125.773 us; speedup 1.0000x reference)
//
#include <hip/hip_runtime.h>
#include <cmath>
#include <complex>

#ifndef M_PI
#define M_PI 3.14159265358979323846
#endif

namespace {

constexpr int NT      = 256;     // threads per block
constexpr int CHUNK   = 32;      // samples per thread
constexpr int WARM    = 32;      // warm-up; |p_max|^32 = 0.7577^32 ~ 1.4e-4 decay
constexpr int T_LEN   = 65536;   // time length per batch row
constexpr int CPR     = T_LEN / CHUNK;   // 2048 chunks per row

struct Coefs { float b0, b1, b2, b3, b4, a1, a2, a3, a4; };

// No LDS, no barriers: thread i's warm-up window IS thread i-1's main chunk,
// so the re-read hits L1 within the same wave. All lines fully consumed.
__global__ __launch_bounds__(NT) void butter_kernel(
        const float* __restrict__ x, float* __restrict__ y, Coefs c) {
    const int g    = blockIdx.x * NT + threadIdx.x;   // global chunk id
    const int row  = g >> 11;                         // g / CPR
    const int cpos = g & (CPR - 1);                   // chunk within row
    const size_t base = ((size_t)row << 16) + ((size_t)cpos << 5);

    // Issue ALL loads up front for max memory-level parallelism.
    float4 wv[WARM / 4];
    float4 mv[CHUNK / 4];
    const bool has_warm = (cpos != 0);
    if (has_warm) {
        const float4* __restrict__ xw = (const float4*)(x + base - WARM);
#pragma unroll
        for (int i = 0; i < WARM / 4; ++i) wv[i] = xw[i];
    }
    const float4* __restrict__ xm = (const float4*)(x + base);
#pragma unroll
    for (int i = 0; i < CHUNK / 4; ++i) mv[i] = xm[i];

    float z0 = 0.f, z1 = 0.f, z2 = 0.f, z3 = 0.f;

    // DF2T step, identical arithmetic to the reference (fp32 coefficients):
    //   y  = b0*x + z0
    //   z0 = z1 + b1*x - a1*y ; z1 = z2 + b2*x - a2*y
    //   z2 = z3 + b3*x - a3*y ; z3 =      b4*x - a4*y
#define STEP_Y(xv, yv)                                   \
    do {                                                 \
        yv = fmaf(c.b0, (xv), z0);                       \
        z0 = fmaf(-c.a1, (yv), fmaf(c.b1, (xv), z1));    \
        z1 = fmaf(-c.a2, (yv), fmaf(c.b2, (xv), z2));    \
        z2 = fmaf(-c.a3, (yv), fmaf(c.b3, (xv), z3));    \
        z3 = fmaf(-c.a4, (yv), c.b4 * (xv));             \
    } while (0)

    if (has_warm) {
#pragma unroll
        for (int i = 0; i < WARM / 4; ++i) {
            float yd;
            STEP_Y(wv[i].x, yd); STEP_Y(wv[i].y, yd);
            STEP_Y(wv[i].z, yd); STEP_Y(wv[i].w, yd);
            (void)yd;
        }
    }
    // cpos==0: zero initial state is exact (reference starts from z=0).

    float4* __restrict__ yo = (float4*)(y + base);
#pragma unroll
    for (int i = 0; i < CHUNK / 4; ++i) {
        float4 ov;
        STEP_Y(mv[i].x, ov.x); STEP_Y(mv[i].y, ov.y);
        STEP_Y(mv[i].z, ov.z); STEP_Y(mv[i].w, ov.w);
        yo[i] = ov;
    }
#undef STEP_Y
}

// Host-side coefficient design: identical math to the reference (double
// precision bilinear-transformed 4th-order Butterworth, cast to fp32).
Coefs make_coefs() {
    const int ORDER = 4;
    const double wn  = 4000.0 / (0.5 * 16000.0);   // 0.5
    const double fs2 = 4.0;
    const double warped = fs2 * std::tan(M_PI * wn / 4.0);
    std::complex<double> pd[4];
    std::complex<double> prod(1.0, 0.0);
    for (int k = 1; k <= ORDER; ++k) {
        double ang = M_PI * (2.0 * k + ORDER - 1.0) / (2.0 * ORDER);
        std::complex<double> p = warped * std::exp(std::complex<double>(0.0, ang));
        prod *= (fs2 - p);
        pd[k - 1] = (fs2 + p) / (fs2 - p);
    }
    double kd = std::pow(warped, ORDER) / prod.real();
    double b[5] = { kd, 4.0 * kd, 6.0 * kd, 4.0 * kd, kd };  // kd * poly(-ones(4))
    std::complex<double> a[5] = { {1,0}, {0,0}, {0,0}, {0,0}, {0,0} };
    for (int k = 0; k < ORDER; ++k)
        for (int j = k + 1; j >= 1; --j) a[j] -= pd[k] * a[j - 1];
    Coefs c;
    c.b0 = (float)b[0]; c.b1 = (float)b[1]; c.b2 = (float)b[2];
    c.b3 = (float)b[3]; c.b4 = (float)b[4];
    c.a1 = (float)a[1].real(); c.a2 = (float)a[2].real();
    c.a3 = (float)a[3].real(); c.a4 = (float)a[4].real();
    return c;
}

} // namespace

extern "C" void kernel_launch(void* const* d_in, const int* in_sizes, int n_in,
                              void* d_out, int out_size, void* d_ws, size_t ws_size,
                              hipStream_t stream) {
    (void)in_sizes; (void)n_in; (void)d_ws; (void)ws_size;
    const float* x = (const float*)d_in[0];
    float* y = (float*)d_out;
    Coefs c = make_coefs();
    const int nchunks = out_size / CHUNK;            // 524288
    const int nblocks = nchunks / NT;                // 2048
    butter_kernel<<<nblocks, NT, 0, stream>>>(x, y, c);
}

// Round 3
// 111.543 us; speedup vs baseline: 1.1276x; 1.1276x over previous
//
#include <hip/hip_runtime.h>
#include <cmath>
#include <complex>

#ifndef M_PI
#define M_PI 3.14159265358979323846
#endif

namespace {

constexpr int NT     = 256;            // threads per block (4 waves)
constexpr int CHUNK  = 32;             // samples per thread
constexpr int WARM   = 32;             // warm-up; |p_max|^32 = 0.7577^32 ~ 1.4e-4 decay
constexpr int REGION = NT * CHUNK;     // 8192 samples = 32 KB LDS exactly
constexpr int T_LEN  = 65536;          // time length per batch row

struct Coefs { float b0, b1, b2, b3, b4, a1, a2, a3, a4; };

// Owner-major rows of 32 floats (8 float4-groups). XOR-swizzle groups by
// owner low bits: any phase's 64-lane b128 access covers all 32 banks per
// 8 lanes -> the 8-fold b128 minimum, conflict-free.
__device__ __forceinline__ int lds_addr4(int o, int tg) {
    return (o << 5) + ((tg ^ (o & 7)) << 2);
}

__global__ __launch_bounds__(NT, 5) void butter_kernel(
        const float* __restrict__ x, float* __restrict__ y, Coefs c) {
    __shared__ float lds[REGION];      // exactly 32 KB -> 5 blocks/CU

    const int tid = threadIdx.x;
    const int bpr = T_LEN / REGION;    // 8 blocks per row
    const int row = blockIdx.x / bpr;
    const int bir = blockIdx.x % bpr;
    const size_t base = (size_t)row * T_LEN + (size_t)bir * REGION;
    const float4* __restrict__ xin = (const float4*)(x + base);

    // ---- Phase 1: coalesced stage region into LDS (loads first for MLP) ----
    float4 sv[8];
#pragma unroll
    for (int k = 0; k < 8; ++k) sv[k] = xin[k * NT + tid];

    // Thread 0's warm window comes from global (previous region tail) or zeros;
    // issued here so its latency overlaps the barrier.
    float4 wv[WARM / 4];
    if (tid == 0) {
#pragma unroll
        for (int i = 0; i < WARM / 4; ++i) wv[i] = make_float4(0.f, 0.f, 0.f, 0.f);
        if (bir != 0) {
            const float4* __restrict__ xw = (const float4*)(x + base - WARM);
#pragma unroll
            for (int i = 0; i < WARM / 4; ++i) wv[i] = xw[i];
        }
    }
#pragma unroll
    for (int k = 0; k < 8; ++k) {
        int i4 = k * NT + tid;
        *(float4*)&lds[lds_addr4(i4 >> 3, i4 & 7)] = sv[k];
    }
    __syncthreads();

    // ---- Phase 2: read warm window = previous thread's chunk (row tid-1) ----
    if (tid != 0) {
#pragma unroll
        for (int tg = 0; tg < WARM / 4; ++tg)
            wv[tg] = *(const float4*)&lds[lds_addr4(tid - 1, tg)];
    }
    __syncthreads();   // all warm reads done before any in-place main writes

    float z0 = 0.f, z1 = 0.f, z2 = 0.f, z3 = 0.f;

    // DF2T step, identical arithmetic to the reference (fp32 coefficients):
    //   y  = b0*x + z0
    //   z0 = z1 + b1*x - a1*y ; z1 = z2 + b2*x - a2*y
    //   z2 = z3 + b3*x - a3*y ; z3 =      b4*x - a4*y
#define STEP_Y(xv, yv)                                   \
    do {                                                 \
        yv = fmaf(c.b0, (xv), z0);                       \
        z0 = fmaf(-c.a1, (yv), fmaf(c.b1, (xv), z1));    \
        z1 = fmaf(-c.a2, (yv), fmaf(c.b2, (xv), z2));    \
        z2 = fmaf(-c.a3, (yv), fmaf(c.b3, (xv), z3));    \
        z3 = fmaf(-c.a4, (yv), c.b4 * (xv));             \
    } while (0)

    // Warm-up (zeros for the very first chunk of a row: exact, zero state).
#pragma unroll
    for (int i = 0; i < WARM / 4; ++i) {
        float yd;
        STEP_Y(wv[i].x, yd); STEP_Y(wv[i].y, yd);
        STEP_Y(wv[i].z, yd); STEP_Y(wv[i].w, yd);
        (void)yd;
    }

    // ---- Phase 3: main chunk (own row), y overwrites x in place ----
#pragma unroll
    for (int tg = 0; tg < CHUNK / 4; ++tg) {
        int a = lds_addr4(tid, tg);
        float4 xv = *(const float4*)&lds[a];
        float4 yv;
        STEP_Y(xv.x, yv.x); STEP_Y(xv.y, yv.y);
        STEP_Y(xv.z, yv.z); STEP_Y(xv.w, yv.w);
        *(float4*)&lds[a] = yv;
    }
#undef STEP_Y
    __syncthreads();

    // ---- Phase 4: coalesced float4 store ----
    float4* __restrict__ yout = (float4*)(y + base);
#pragma unroll
    for (int k = 0; k < 8; ++k) {
        int i4 = k * NT + tid;
        yout[i4] = *(const float4*)&lds[lds_addr4(i4 >> 3, i4 & 7)];
    }
}

// Host-side coefficient design: identical math to the reference (double
// precision bilinear-transformed 4th-order Butterworth, cast to fp32).
Coefs make_coefs() {
    const int ORDER = 4;
    const double wn  = 4000.0 / (0.5 * 16000.0);   // 0.5
    const double fs2 = 4.0;
    const double warped = fs2 * std::tan(M_PI * wn / 4.0);
    std::complex<double> pd[4];
    std::complex<double> prod(1.0, 0.0);
    for (int k = 1; k <= ORDER; ++k) {
        double ang = M_PI * (2.0 * k + ORDER - 1.0) / (2.0 * ORDER);
        std::complex<double> p = warped * std::exp(std::complex<double>(0.0, ang));
        prod *= (fs2 - p);
        pd[k - 1] = (fs2 + p) / (fs2 - p);
    }
    double kd = std::pow(warped, ORDER) / prod.real();
    double b[5] = { kd, 4.0 * kd, 6.0 * kd, 4.0 * kd, kd };  // kd * poly(-ones(4))
    std::complex<double> a[5] = { {1,0}, {0,0}, {0,0}, {0,0}, {0,0} };
    for (int k = 0; k < ORDER; ++k)
        for (int j = k + 1; j >= 1; --j) a[j] -= pd[k] * a[j - 1];
    Coefs c;
    c.b0 = (float)b[0]; c.b1 = (float)b[1]; c.b2 = (float)b[2];
    c.b3 = (float)b[3]; c.b4 = (float)b[4];
    c.a1 = (float)a[1].real(); c.a2 = (float)a[2].real();
    c.a3 = (float)a[3].real(); c.a4 = (float)a[4].real();
    return c;
}

} // namespace

extern "C" void kernel_launch(void* const* d_in, const int* in_sizes, int n_in,
                              void* d_out, int out_size, void* d_ws, size_t ws_size,
                              hipStream_t stream) {
    (void)in_sizes; (void)n_in; (void)d_ws; (void)ws_size;
    const float* x = (const float*)d_in[0];
    float* y = (float*)d_out;
    Coefs c = make_coefs();
    const int nblocks = out_size / REGION;   // 256*65536/8192 = 2048
    butter_kernel<<<nblocks, NT, 0, stream>>>(x, y, c);
}

// Round 4
// 110.369 us; speedup vs baseline: 1.1396x; 1.0106x over previous
//
#include <hip/hip_runtime.h>
#include <cmath>
#include <complex>

#ifndef M_PI
#define M_PI 3.14159265358979323846
#endif

namespace {

constexpr int NT     = 256;            // threads per block (4 waves)
constexpr int CHUNK  = 32;             // samples per thread
constexpr int WARM   = 32;             // warm-up; |p_max|^32 = 0.7577^32 ~ 1.4e-4 decay
constexpr int REGION = NT * CHUNK;     // 8192 samples = 32 KB LDS exactly
constexpr int T_LEN  = 65536;          // time length per batch row

struct Coefs { float b0, b1, b2, b3, b4, a1, a2, a3, a4; };

// Owner-major rows of 32 floats (8 float4-groups), groups XOR-swizzled by
// owner low bits. Every phase's 64-lane b128 access then hits each bank
// exactly 8 words = the b128 minimum, conflict-free (verified for all four
// access patterns: stage-write, row-read, y-write, store-read).
__device__ __forceinline__ int lds_addr4(int o, int tg) {
    return (o << 5) + ((tg ^ (o & 7)) << 2);
}

__global__ __launch_bounds__(NT, 5) void butter_kernel(
        const float* __restrict__ x, float* __restrict__ y, Coefs c) {
    __shared__ float lds[REGION];      // exactly 32 KB -> 5 blocks/CU

    const int tid = threadIdx.x;
    const int bpr = T_LEN / REGION;    // 8 blocks per row
    const int row = blockIdx.x / bpr;
    const int bir = blockIdx.x % bpr;
    const size_t base = (size_t)row * T_LEN + (size_t)bir * REGION;
    const float4* __restrict__ xin = (const float4*)(x + base);

    // ---- Stage region (coalesced) + lane-0 warm windows (global) ----
    float4 sv[8];
#pragma unroll
    for (int k = 0; k < 8; ++k) sv[k] = xin[k * NT + tid];

    const bool lane0 = ((tid & 63) == 0);
    float4 wv[WARM / 4];
    if (lane0) {
        // Wave-leading lanes can't read row tid-1 intra-wave; fetch the
        // 128 B warm window straight from global (L2-hot, ~2 lines each).
#pragma unroll
        for (int i = 0; i < WARM / 4; ++i) wv[i] = make_float4(0.f, 0.f, 0.f, 0.f);
        if (!(bir == 0 && tid == 0)) {   // very first chunk of a row: zero state exact
            const float4* __restrict__ xw =
                (const float4*)(x + base + (size_t)tid * CHUNK - WARM);
#pragma unroll
            for (int i = 0; i < WARM / 4; ++i) wv[i] = xw[i];
        }
    }

#pragma unroll
    for (int k = 0; k < 8; ++k) {
        int i4 = k * NT + tid;
        *(float4*)&lds[lds_addr4(i4 >> 3, i4 & 7)] = sv[k];
    }
    __syncthreads();   // the ONLY block-wide barrier (staging scatters across waves)

    // ---- Warm window from LDS (row tid-1: same wave for all non-lane0) ----
    if (!lane0) {
#pragma unroll
        for (int tg = 0; tg < WARM / 4; ++tg)
            wv[tg] = *(const float4*)&lds[lds_addr4(tid - 1, tg)];
    }
    // Own chunk (row tid).
    float4 mv[CHUNK / 4];
#pragma unroll
    for (int tg = 0; tg < CHUNK / 4; ++tg)
        mv[tg] = *(const float4*)&lds[lds_addr4(tid, tg)];

    float z0 = 0.f, z1 = 0.f, z2 = 0.f, z3 = 0.f;

    // DF2T step, identical arithmetic to the reference (fp32 coefficients):
    //   y  = b0*x + z0
    //   z0 = z1 + b1*x - a1*y ; z1 = z2 + b2*x - a2*y
    //   z2 = z3 + b3*x - a3*y ; z3 =      b4*x - a4*y
#define STEP_Y(xv, yv)                                   \
    do {                                                 \
        yv = fmaf(c.b0, (xv), z0);                       \
        z0 = fmaf(-c.a1, (yv), fmaf(c.b1, (xv), z1));    \
        z1 = fmaf(-c.a2, (yv), fmaf(c.b2, (xv), z2));    \
        z2 = fmaf(-c.a3, (yv), fmaf(c.b3, (xv), z3));    \
        z3 = fmaf(-c.a4, (yv), c.b4 * (xv));             \
    } while (0)

#pragma unroll
    for (int i = 0; i < WARM / 4; ++i) {
        float yd;
        STEP_Y(wv[i].x, yd); STEP_Y(wv[i].y, yd);
        STEP_Y(wv[i].z, yd); STEP_Y(wv[i].w, yd);
        (void)yd;
    }

    // ---- Main chunk: y overwrites row tid in LDS.
    // Safe vs lane tid+1's warm read of row tid: that read precedes these
    // writes in program order AND is a data-predecessor of them; per-wave DS
    // ops execute in order.
#pragma unroll
    for (int tg = 0; tg < CHUNK / 4; ++tg) {
        float4 yv;
        STEP_Y(mv[tg].x, yv.x); STEP_Y(mv[tg].y, yv.y);
        STEP_Y(mv[tg].z, yv.z); STEP_Y(mv[tg].w, yv.w);
        *(float4*)&lds[lds_addr4(tid, tg)] = yv;
    }
#undef STEP_Y

    // Compiler fence: store-phase reads below touch only rows written by
    // THIS wave's lanes (wave w stores float4s [w*512, w*512+512) = rows
    // [w*64, w*64+64)). Intra-wave + in-order DS pipeline = no __syncthreads.
    asm volatile("" ::: "memory");
    __builtin_amdgcn_wave_barrier();

    // ---- Coalesced store, wave-local rows only ----
    const int w = tid >> 6, l = tid & 63;
    float4* __restrict__ yout = (float4*)(y + base);
#pragma unroll
    for (int j = 0; j < 8; ++j) {
        int i4 = (w << 9) + (j << 6) + l;
        yout[i4] = *(const float4*)&lds[lds_addr4(i4 >> 3, i4 & 7)];
    }
}

// Host-side coefficient design: identical math to the reference (double
// precision bilinear-transformed 4th-order Butterworth, cast to fp32).
Coefs make_coefs() {
    const int ORDER = 4;
    const double wn  = 4000.0 / (0.5 * 16000.0);   // 0.5
    const double fs2 = 4.0;
    const double warped = fs2 * std::tan(M_PI * wn / 4.0);
    std::complex<double> pd[4];
    std::complex<double> prod(1.0, 0.0);
    for (int k = 1; k <= ORDER; ++k) {
        double ang = M_PI * (2.0 * k + ORDER - 1.0) / (2.0 * ORDER);
        std::complex<double> p = warped * std::exp(std::complex<double>(0.0, ang));
        prod *= (fs2 - p);
        pd[k - 1] = (fs2 + p) / (fs2 - p);
    }
    double kd = std::pow(warped, ORDER) / prod.real();
    double b[5] = { kd, 4.0 * kd, 6.0 * kd, 4.0 * kd, kd };  // kd * poly(-ones(4))
    std::complex<double> a[5] = { {1,0}, {0,0}, {0,0}, {0,0}, {0,0} };
    for (int k = 0; k < ORDER; ++k)
        for (int j = k + 1; j >= 1; --j) a[j] -= pd[k] * a[j - 1];
    Coefs c;
    c.b0 = (float)b[0]; c.b1 = (float)b[1]; c.b2 = (float)b[2];
    c.b3 = (float)b[3]; c.b4 = (float)b[4];
    c.a1 = (float)a[1].real(); c.a2 = (float)a[2].real();
    c.a3 = (float)a[3].real(); c.a4 = (float)a[4].real();
    return c;
}

} // namespace

extern "C" void kernel_launch(void* const* d_in, const int* in_sizes, int n_in,
                              void* d_out, int out_size, void* d_ws, size_t ws_size,
                              hipStream_t stream) {
    (void)in_sizes; (void)n_in; (void)d_ws; (void)ws_size;
    const float* x = (const float*)d_in[0];
    float* y = (float*)d_out;
    Coefs c = make_coefs();
    const int nblocks = out_size / REGION;   // 256*65536/8192 = 2048
    butter_kernel<<<nblocks, NT, 0, stream>>>(x, y, c);
}